// Round 1
// baseline (919.917 us; speedup 1.0000x reference)
//
#include <hip/hip_runtime.h>

constexpr int F  = 32;
constexpr int V  = 10000;
constexpr int D  = 496;     // 124 float4
constexpr int H  = 1024;
constexpr int NT = 128;     // threads per block (2 waves)

__global__ __launch_bounds__(NT) void deepqi_fused(
    const float* __restrict__ xv,   // [B,F]
    const int*   __restrict__ xi,   // [B,F]
    const float* __restrict__ emb,  // [F,V,D]
    const float* __restrict__ W1,   // [F,H]
    const float* __restrict__ b1,   // [H]
    const float* __restrict__ W2,   // [D+H,1]
    const float* __restrict__ b2,   // [1]
    float* __restrict__ out)        // [B]
{
    const int b = blockIdx.x;
    const int t = threadIdx.x;

    __shared__ float s_xv[F];
    __shared__ int   s_xi[F];
    __shared__ float s_wsum[NT / 64];

    if (t < F) {
        s_xv[t] = xv[b * F + t];
        s_xi[t] = xi[b * F + t];
    }
    __syncthreads();

    float acc = 0.0f;

    // ---------- FM interaction: thread t owns d in [4t, 4t+4) ----------
    if (t < D / 4) {
        float4 s  = make_float4(0.f, 0.f, 0.f, 0.f);
        float4 ss = make_float4(0.f, 0.f, 0.f, 0.f);
        #pragma unroll 4
        for (int f = 0; f < F; ++f) {
            const float xf = s_xv[f];
            const float* row = emb + ((size_t)f * V + (size_t)s_xi[f]) * D;
            float4 v = *reinterpret_cast<const float4*>(row + 4 * t);
            v.x *= xf; v.y *= xf; v.z *= xf; v.w *= xf;
            s.x  += v.x;       s.y  += v.y;       s.z  += v.z;       s.w  += v.w;
            ss.x += v.x * v.x; ss.y += v.y * v.y; ss.z += v.z * v.z; ss.w += v.w * v.w;
        }
        float4 w = *reinterpret_cast<const float4*>(W2 + 4 * t);
        float qx = 0.5f * (s.x * s.x - ss.x);
        float qy = 0.5f * (s.y * s.y - ss.y);
        float qz = 0.5f * (s.z * s.z - ss.z);
        float qw = 0.5f * (s.w * s.w - ss.w);
        acc = qx * w.x + qy * w.y + qz * w.z + qw * w.w;
    }

    // ---------- MLP branch: thread t owns j in [8t, 8t+8) ----------
    float xr[F];
    #pragma unroll
    for (int f = 0; f < F; ++f) xr[f] = s_xv[f];

    {
        const int j0 = 8 * t;
        float4 ba = *reinterpret_cast<const float4*>(b1 + j0);
        float4 bb = *reinterpret_cast<const float4*>(b1 + j0 + 4);
        float h0 = ba.x, h1 = ba.y, h2 = ba.z, h3 = ba.w;
        float h4 = bb.x, h5 = bb.y, h6 = bb.z, h7 = bb.w;
        #pragma unroll 4
        for (int f = 0; f < F; ++f) {
            const float xf = xr[f];
            float4 wa = *reinterpret_cast<const float4*>(W1 + f * H + j0);
            float4 wb = *reinterpret_cast<const float4*>(W1 + f * H + j0 + 4);
            h0 += xf * wa.x; h1 += xf * wa.y; h2 += xf * wa.z; h3 += xf * wa.w;
            h4 += xf * wb.x; h5 += xf * wb.y; h6 += xf * wb.z; h7 += xf * wb.w;
        }
        float4 wa = *reinterpret_cast<const float4*>(W2 + D + j0);
        float4 wb = *reinterpret_cast<const float4*>(W2 + D + j0 + 4);
        acc += fmaxf(h0, 0.f) * wa.x + fmaxf(h1, 0.f) * wa.y
             + fmaxf(h2, 0.f) * wa.z + fmaxf(h3, 0.f) * wa.w
             + fmaxf(h4, 0.f) * wb.x + fmaxf(h5, 0.f) * wb.y
             + fmaxf(h6, 0.f) * wb.z + fmaxf(h7, 0.f) * wb.w;
    }

    // ---------- block reduction ----------
    #pragma unroll
    for (int off = 32; off > 0; off >>= 1)
        acc += __shfl_down(acc, off, 64);
    if ((t & 63) == 0) s_wsum[t >> 6] = acc;
    __syncthreads();
    if (t == 0) out[b] = s_wsum[0] + s_wsum[1] + b2[0];
}

extern "C" void kernel_launch(void* const* d_in, const int* in_sizes, int n_in,
                              void* d_out, int out_size, void* d_ws, size_t ws_size,
                              hipStream_t stream) {
    const float* xv  = (const float*)d_in[0];
    const int*   xi  = (const int*)d_in[1];
    const float* emb = (const float*)d_in[2];
    const float* W1  = (const float*)d_in[3];
    const float* b1  = (const float*)d_in[4];
    const float* W2  = (const float*)d_in[5];
    const float* b2  = (const float*)d_in[6];
    float* out = (float*)d_out;

    const int B = in_sizes[0] / F;
    deepqi_fused<<<B, NT, 0, stream>>>(xv, xi, emb, W1, b1, W2, b2, out);
}

// Round 2
// 889.477 us; speedup vs baseline: 1.0342x; 1.0342x over previous
//
#include <hip/hip_runtime.h>

constexpr int F  = 32;
constexpr int V  = 10000;
constexpr int D  = 496;     // 124 float4
constexpr int H  = 1024;
constexpr int NT = 128;     // threads per block (2 waves)

__global__ __launch_bounds__(NT, 4) void deepqi_fused(
    const float* __restrict__ xv,   // [B,F]
    const int*   __restrict__ xi,   // [B,F]
    const float* __restrict__ emb,  // [F,V,D]
    const float* __restrict__ W1,   // [F,H]
    const float* __restrict__ b1,   // [H]
    const float* __restrict__ W2,   // [D+H,1]
    const float* __restrict__ b2,   // [1]
    float* __restrict__ out)        // [B]
{
    const int b = blockIdx.x;
    const int t = threadIdx.x;

    __shared__ float        s_xv[F];
    __shared__ const float* s_row[F];   // precomputed gather-row base pointers
    __shared__ float        s_wsum[NT / 64];

    if (t < F) {
        s_xv[t]  = xv[b * F + t];
        s_row[t] = emb + ((size_t)t * V + (size_t)xi[b * F + t]) * D;
    }
    __syncthreads();

    float acc = 0.0f;

    // ---------- FM interaction: thread t owns d in [4t, 4t+4) ----------
    if (t < D / 4) {
        float4 s  = make_float4(0.f, 0.f, 0.f, 0.f);
        float4 ss = make_float4(0.f, 0.f, 0.f, 0.f);
        #pragma unroll 8
        for (int f = 0; f < F; ++f) {
            const float xf = s_xv[f];
            float4 v = *reinterpret_cast<const float4*>(s_row[f] + 4 * t);
            v.x *= xf; v.y *= xf; v.z *= xf; v.w *= xf;
            s.x  += v.x;       s.y  += v.y;       s.z  += v.z;       s.w  += v.w;
            ss.x += v.x * v.x; ss.y += v.y * v.y; ss.z += v.z * v.z; ss.w += v.w * v.w;
        }
        float4 w = *reinterpret_cast<const float4*>(W2 + 4 * t);
        float qx = 0.5f * (s.x * s.x - ss.x);
        float qy = 0.5f * (s.y * s.y - ss.y);
        float qz = 0.5f * (s.z * s.z - ss.z);
        float qw = 0.5f * (s.w * s.w - ss.w);
        acc = qx * w.x + qy * w.y + qz * w.z + qw * w.w;
    }

    // ---------- MLP branch: thread t owns j in [8t, 8t+8) ----------
    {
        const int j0 = 8 * t;
        float4 ba = *reinterpret_cast<const float4*>(b1 + j0);
        float4 bb = *reinterpret_cast<const float4*>(b1 + j0 + 4);
        float h0 = ba.x, h1 = ba.y, h2 = ba.z, h3 = ba.w;
        float h4 = bb.x, h5 = bb.y, h6 = bb.z, h7 = bb.w;
        #pragma unroll 4
        for (int f = 0; f < F; ++f) {
            const float xf = s_xv[f];   // LDS broadcast, no register array / scratch
            float4 wa = *reinterpret_cast<const float4*>(W1 + f * H + j0);
            float4 wb = *reinterpret_cast<const float4*>(W1 + f * H + j0 + 4);
            h0 += xf * wa.x; h1 += xf * wa.y; h2 += xf * wa.z; h3 += xf * wa.w;
            h4 += xf * wb.x; h5 += xf * wb.y; h6 += xf * wb.z; h7 += xf * wb.w;
        }
        float4 wa = *reinterpret_cast<const float4*>(W2 + D + j0);
        float4 wb = *reinterpret_cast<const float4*>(W2 + D + j0 + 4);
        acc += fmaxf(h0, 0.f) * wa.x + fmaxf(h1, 0.f) * wa.y
             + fmaxf(h2, 0.f) * wa.z + fmaxf(h3, 0.f) * wa.w
             + fmaxf(h4, 0.f) * wb.x + fmaxf(h5, 0.f) * wb.y
             + fmaxf(h6, 0.f) * wb.z + fmaxf(h7, 0.f) * wb.w;
    }

    // ---------- block reduction ----------
    #pragma unroll
    for (int off = 32; off > 0; off >>= 1)
        acc += __shfl_down(acc, off, 64);
    if ((t & 63) == 0) s_wsum[t >> 6] = acc;
    __syncthreads();
    if (t == 0) out[b] = s_wsum[0] + s_wsum[1] + b2[0];
}

extern "C" void kernel_launch(void* const* d_in, const int* in_sizes, int n_in,
                              void* d_out, int out_size, void* d_ws, size_t ws_size,
                              hipStream_t stream) {
    const float* xv  = (const float*)d_in[0];
    const int*   xi  = (const int*)d_in[1];
    const float* emb = (const float*)d_in[2];
    const float* W1  = (const float*)d_in[3];
    const float* b1  = (const float*)d_in[4];
    const float* W2  = (const float*)d_in[5];
    const float* b2  = (const float*)d_in[6];
    float* out = (float*)d_out;

    const int B = in_sizes[0] / F;
    deepqi_fused<<<B, NT, 0, stream>>>(xv, xi, emb, W1, b1, W2, b2, out);
}